// Round 10
// baseline (497.226 us; speedup 1.0000x reference)
//
#include <hip/hip_runtime.h>
#include <math.h>

#define CIN  256
#define MEDC 128
#define KOUT 128
#define HWSZ 6400   // 80*80
#define NB   16
#define TP   16     // pixels per block

typedef unsigned int u32;
typedef unsigned long long u64;

// Bit-exact emulation of numpy's SIMD float32 exp (Cephes expf with FMA).
__device__ __forceinline__ float numpy_expf(float x) {
#pragma clang fp contract(off)
    const float q = __builtin_rintf(x * 1.44269504088896341f);
    float r = __builtin_fmaf(q, -0.693359375f, x);
    r = __builtin_fmaf(q, 2.12194440e-4f, r);
    float p = __builtin_fmaf(1.9875691500e-4f, r, 1.3981999507e-3f);
    p = __builtin_fmaf(p, r, 8.3334519073e-3f);
    p = __builtin_fmaf(p, r, 4.1665795894e-2f);
    p = __builtin_fmaf(p, r, 1.6666665459e-1f);
    p = __builtin_fmaf(p, r, 5.0000001201e-1f);
    const float r2 = r * r;
    p = __builtin_fmaf(p, r2, r);
    p = p + 1.0f;
    return __builtin_ldexpf(p, (int)q);
}

__global__ void prep_T(const float* __restrict__ w1, const float* __restrict__ w2,
                       float* __restrict__ w1t, float* __restrict__ w2t) {
    const int c = blockIdx.x;    // 256
    const int m = threadIdx.x;   // 128
    w1t[c * MEDC + m] = w1[m * CIN + c];
    // w2t permuted so channels {q, q+64, q+128, q+192} form one float4:
    // w2t[m][4q + ci] = w2[q + 64*ci][m]
    const int q  = c & 63;
    const int ci = c >> 6;
    w2t[m * CIN + q * 4 + ci] = w2[c * MEDC + m];
}

// ---------- flip-merge bitonic sort: 256 keys as positive f64 denormals ----------
// position e = 16*u + r  (u = lane-in-16, r = reg) ; fully ascending network.
// Keys: ((u64)sig_bits << 8) | (255 - c)  < 2^40  -> positive f64 denormal,
// IEEE-ordered identically to u64 compare; f64 denorms never flushed; all keys
// distinct (channel payload) so min/max ties are impossible.

template<int MASK>
__device__ __forceinline__ void intraX(double (&k)[16]) {
#pragma unroll
    for (int r = 0; r < 16; ++r) {
        if (r < (r ^ MASK)) {
            const double a = k[r], bb = k[r ^ MASK];
            k[r]        = fmin(a, bb);
            k[r ^ MASK] = fmax(a, bb);
        }
    }
}

template<int SWZ>
__device__ __forceinline__ double swzd(double v) {
    const u64 x = (u64)__double_as_longlong(v);
    const int lo = __builtin_amdgcn_ds_swizzle((int)(u32)x, SWZ);
    const int hi = __builtin_amdgcn_ds_swizzle((int)(u32)(x >> 32), SWZ);
    return __longlong_as_double((long long)(((u64)(u32)hi << 32) | (u64)(u32)lo));
}

// flip substep of merge L: pair e <-> e^(L-1): lane u <-> u^M (SWZ), reg r <-> r^15
template<int SWZ, int UB>
__device__ __forceinline__ void crossFlip(double (&k)[16], const int u) {
    const bool keepmin = (u & UB) == 0;
#pragma unroll
    for (int r = 0; r < 8; ++r) {
        const int q = r ^ 15;
        const double o1 = swzd<SWZ>(k[q]);   // partner's old k[q]
        const double o2 = swzd<SWZ>(k[r]);   // partner's old k[r]
        const double mn1 = fmin(k[r], o1), mx1 = fmax(k[r], o1);
        const double mn2 = fmin(k[q], o2), mx2 = fmax(k[q], o2);
        k[r] = keepmin ? mn1 : mx1;
        k[q] = keepmin ? mn2 : mx2;
    }
}

// uniform cross substep: pair lane u <-> u^M, same reg
template<int SWZ, int UB>
__device__ __forceinline__ void crossU(double (&k)[16], const int u) {
    const bool keepmin = (u & UB) == 0;
#pragma unroll
    for (int r = 0; r < 16; ++r) {
        const double o = swzd<SWZ>(k[r]);
        const double mn = fmin(k[r], o), mx = fmax(k[r], o);
        k[r] = keepmin ? mn : mx;
    }
}

// __launch_bounds__(256,3): allocator empirically targets ~2x min-waves ->
// ~6 waves/EU -> ~80-85 VGPR budget. Kernel peak ~75-80 -> no spill, and
// runtime occupancy lands at ~6 blocks/CU (VGPR-bound; LDS permits 8).
__global__ __launch_bounds__(256, 3)
void csel_main(const float* __restrict__ x,
               const float* __restrict__ w1t, const float* __restrict__ w2t,
               const float* __restrict__ b1, const float* __restrict__ b2,
               float* __restrict__ out) {
    // xs: x tile (stride 20), later overwritten in-place with prod = x * x_
    // ONLY LDS buffer: 20480 B
    __shared__ __align__(16) float xs[CIN * 20];

    const int t    = threadIdx.x;
    const int pix0 = blockIdx.x * TP;
    const int b    = pix0 / HWSZ;
    const int hw0  = pix0 % HWSZ;
    const float* xb = x + (size_t)b * CIN * HWSZ + hw0;

    // ---- stage x tile: 256 channels x 16 pixels ----
    {
        const int p  = t & (TP - 1);
        const int c0 = t >> 4;
        #pragma unroll
        for (int i = 0; i < 16; ++i) {
            const int c = c0 + i * 16;
            xs[c * 20 + p] = xb[(size_t)c * HWSZ + p];
        }
    }
    __syncthreads();

    // ---- GEMM1: h[m][p] = sequential fp32 FMA chain over c ascending ----
    // Lane lw of wave wq computes m = {2lw, 2lw+1} for pixels {4wq..4wq+3}.
    const int lw = t & 63;
    const int wq = t >> 6;
    const int ml = lw * 2;
    const float b1a = b1[ml];
    const float b1b = b1[ml + 1];
    float a1[2][4] = {{0.f,0.f,0.f,0.f},{0.f,0.f,0.f,0.f}};

    #pragma unroll 4
    for (int c = 0; c < CIN; ++c) {
        const float2 wv = *(const float2*)&w1t[c * MEDC + ml];
        const float4 xv = *(const float4*)&xs[c * 20 + wq * 4];   // wave-uniform broadcast
        a1[0][0] = fmaf(wv.x, xv.x, a1[0][0]);
        a1[0][1] = fmaf(wv.x, xv.y, a1[0][1]);
        a1[0][2] = fmaf(wv.x, xv.z, a1[0][2]);
        a1[0][3] = fmaf(wv.x, xv.w, a1[0][3]);
        a1[1][0] = fmaf(wv.y, xv.x, a1[1][0]);
        a1[1][1] = fmaf(wv.y, xv.y, a1[1][1]);
        a1[1][2] = fmaf(wv.y, xv.z, a1[1][2]);
        a1[1][3] = fmaf(wv.y, xv.w, a1[1][3]);
    }
    // h stays in registers: h8[(m&1)*4 + pj] on lane m>>1
    float h8[8];
    #pragma unroll
    for (int j = 0; j < 4; ++j) {
        h8[j]     = a1[0][j] + b1a;
        h8[4 + j] = a1[1][j] + b1b;
    }

    // ---- GEMM2: wave-local, zero LDS. Lane lw owns channels {lw+64ci} x pixels {4wq+pj}.
    // h[m][4wq+pj] broadcast from lane m>>1 via v_readlane (compile-time lane+reg).
    const float b2v0 = b2[lw];
    const float b2v1 = b2[lw + 64];
    const float b2v2 = b2[lw + 128];
    const float b2v3 = b2[lw + 192];
    const float* w2p = w2t + lw * 4;

    float4 wbuf[4];
    #pragma unroll
    for (int m0 = 0; m0 < 4; ++m0)
        wbuf[m0] = *(const float4*)&w2p[m0 * CIN];

    float a2[4][4];
    #pragma unroll
    for (int i = 0; i < 4; ++i)
        #pragma unroll
        for (int j = 0; j < 4; ++j) a2[i][j] = 0.f;

    #pragma unroll
    for (int m = 0; m < MEDC; ++m) {
        const float4 wv = wbuf[m & 3];
        float hb[4];
        #pragma unroll
        for (int pj = 0; pj < 4; ++pj) {
            const int reg = (m & 1) * 4 + pj;              // compile-time
            hb[pj] = __int_as_float(
                __builtin_amdgcn_readlane(__float_as_int(h8[reg]), m >> 1));
        }
        a2[0][0] = fmaf(wv.x, hb[0], a2[0][0]);
        a2[0][1] = fmaf(wv.x, hb[1], a2[0][1]);
        a2[0][2] = fmaf(wv.x, hb[2], a2[0][2]);
        a2[0][3] = fmaf(wv.x, hb[3], a2[0][3]);
        a2[1][0] = fmaf(wv.y, hb[0], a2[1][0]);
        a2[1][1] = fmaf(wv.y, hb[1], a2[1][1]);
        a2[1][2] = fmaf(wv.y, hb[2], a2[1][2]);
        a2[1][3] = fmaf(wv.y, hb[3], a2[1][3]);
        a2[2][0] = fmaf(wv.z, hb[0], a2[2][0]);
        a2[2][1] = fmaf(wv.z, hb[1], a2[2][1]);
        a2[2][2] = fmaf(wv.z, hb[2], a2[2][2]);
        a2[2][3] = fmaf(wv.z, hb[3], a2[2][3]);
        a2[3][0] = fmaf(wv.w, hb[0], a2[3][0]);
        a2[3][1] = fmaf(wv.w, hb[1], a2[3][1]);
        a2[3][2] = fmaf(wv.w, hb[2], a2[3][2]);
        a2[3][3] = fmaf(wv.w, hb[3], a2[3][3]);
        if (m + 4 < MEDC)
            wbuf[m & 3] = *(const float4*)&w2p[(m + 4) * CIN];
    }
    float xv32[4][4];
    #pragma unroll
    for (int pj = 0; pj < 4; ++pj) {
        xv32[0][pj] = a2[0][pj] + b2v0;
        xv32[1][pj] = a2[1][pj] + b2v1;
        xv32[2][pj] = a2[2][pj] + b2v2;
        xv32[3][pj] = a2[3][pj] + b2v3;
    }
    __syncthreads();   // all GEMM1 xs reads complete before prod overwrites xs

    // ---- sigmoid bits -> registers; prod = x * x_ in-place over xs ----
    u32 sv[4][4];
    #pragma unroll
    for (int ci = 0; ci < 4; ++ci) {
        const int c = lw + 64 * ci;
        #pragma unroll
        for (int pj = 0; pj < 4; ++pj) {
#pragma clang fp contract(off)
            const int p2 = wq * 4 + pj;
            const float e  = numpy_expf(-xv32[ci][pj]);
            const float dd = 1.0f + e;
            const float s  = 1.0f / dd;
            sv[ci][pj] = __float_as_uint(s);
            xs[c * 20 + p2] = xs[c * 20 + p2] * xv32[ci][pj];
        }
    }
    __syncthreads();   // prod writes complete before epilogue gathers (sort is reg-only)

    // ---- 4x4 register transpose over (lane-quarter a, pixel-reg b) ----
    // After: lane (a,u), reg b, ci holds sig bits of channel c = u + 16b + 64ci,
    // pixel 4wq + a  (= this lane's own sort pixel t>>4).
    const int a0 = (t >> 4) & 1;
    const int a1b = (t >> 5) & 1;
    #pragma unroll
    for (int ci = 0; ci < 4; ++ci) {
        {   // round 1: partner lane^16, pairs (b, b^1)
            const u32 s0 = (u32)__builtin_amdgcn_ds_swizzle((int)sv[ci][1], 0x401F);
            const u32 s1 = (u32)__builtin_amdgcn_ds_swizzle((int)sv[ci][0], 0x401F);
            const u32 s2 = (u32)__builtin_amdgcn_ds_swizzle((int)sv[ci][3], 0x401F);
            const u32 s3 = (u32)__builtin_amdgcn_ds_swizzle((int)sv[ci][2], 0x401F);
            sv[ci][0] = a0 ? s0 : sv[ci][0];
            sv[ci][1] = a0 ? sv[ci][1] : s1;
            sv[ci][2] = a0 ? s2 : sv[ci][2];
            sv[ci][3] = a0 ? sv[ci][3] : s3;
        }
        {   // round 2: partner lane^32, pairs (b, b^2)
            const u32 s0 = (u32)__shfl_xor((int)sv[ci][2], 32, 64);
            const u32 s1 = (u32)__shfl_xor((int)sv[ci][3], 32, 64);
            const u32 s2 = (u32)__shfl_xor((int)sv[ci][0], 32, 64);
            const u32 s3 = (u32)__shfl_xor((int)sv[ci][1], 32, 64);
            sv[ci][0] = a1b ? s0 : sv[ci][0];
            sv[ci][1] = a1b ? s1 : sv[ci][1];
            sv[ci][2] = a1b ? sv[ci][2] : s2;
            sv[ci][3] = a1b ? sv[ci][3] : s3;
        }
    }

    // ---- build keys: k[r] holds channel c = u + 16r of this lane's pixel ----
    const int u = t & 15;
    double k[16];
    #pragma unroll
    for (int ci = 0; ci < 4; ++ci) {
        #pragma unroll
        for (int bb = 0; bb < 4; ++bb) {
            const int r = bb + 4 * ci;
            const u64 key = ((u64)sv[ci][bb] << 8) | (u64)(255 - (u + 16 * r));
            k[r] = __longlong_as_double((long long)key);
        }
    }

    // ---- flip-merge bitonic sort, all-ascending min/max network ----
    intraX<1>(k);                                                      // L=2
    intraX<3>(k); intraX<1>(k);                                        // L=4
    intraX<7>(k); intraX<2>(k); intraX<1>(k);                          // L=8
    intraX<15>(k); intraX<4>(k); intraX<2>(k); intraX<1>(k);           // L=16
    crossFlip<0x041F,1>(k,u);                                          // L=32
    intraX<8>(k); intraX<4>(k); intraX<2>(k); intraX<1>(k);
    crossFlip<0x0C1F,2>(k,u); crossU<0x041F,1>(k,u);                   // L=64
    intraX<8>(k); intraX<4>(k); intraX<2>(k); intraX<1>(k);
    crossFlip<0x1C1F,4>(k,u); crossU<0x081F,2>(k,u); crossU<0x041F,1>(k,u);   // L=128
    intraX<8>(k); intraX<4>(k); intraX<2>(k); intraX<1>(k);
    crossFlip<0x3C1F,8>(k,u); crossU<0x101F,4>(k,u); crossU<0x081F,2>(k,u); crossU<0x041F,1>(k,u); // L=256
    intraX<8>(k); intraX<4>(k); intraX<2>(k); intraX<1>(k);

    // ---- epilogue: positions e=16u+r, e>=128 hold ranks 127..0 ----
    const int p = t >> 4;
    if (u >= 8) {
        const int rbase = 255 - u * 16;    // rank = rbase - r
        float* ob = out + (size_t)b * KOUT * HWSZ + hw0 + p;
        #pragma unroll
        for (int r = 0; r < 16; ++r) {
            const u64 kb = (u64)__double_as_longlong(k[r]);
            const int c = 255 - (int)(kb & 0xFF);
            ob[(size_t)(rbase - r) * HWSZ] = xs[c * 20 + p];
        }
    }
}

extern "C" void kernel_launch(void* const* d_in, const int* in_sizes, int n_in,
                              void* d_out, int out_size, void* d_ws, size_t ws_size,
                              hipStream_t stream) {
    const float* x  = (const float*)d_in[0];
    const float* w1 = (const float*)d_in[1];
    const float* b1 = (const float*)d_in[2];
    const float* w2 = (const float*)d_in[3];
    const float* b2 = (const float*)d_in[4];

    float* w1t = (float*)d_ws;              // 128 KB
    float* w2t = w1t + CIN * MEDC;          // 128 KB

    prep_T<<<CIN, MEDC, 0, stream>>>(w1, w2, w1t, w2t);
    csel_main<<<(NB * HWSZ) / TP, 256, 0, stream>>>(x, w1t, w2t, b1, b2, (float*)d_out);
}

// Round 11
// 480.407 us; speedup vs baseline: 1.0350x; 1.0350x over previous
//
#include <hip/hip_runtime.h>
#include <math.h>

#define CIN  256
#define MEDC 128
#define KOUT 128
#define HWSZ 6400   // 80*80
#define NB   16
#define TP   16     // pixels per block

typedef unsigned int u32;
typedef unsigned long long u64;

// Bit-exact emulation of numpy's SIMD float32 exp (Cephes expf with FMA).
__device__ __forceinline__ float numpy_expf(float x) {
#pragma clang fp contract(off)
    const float q = __builtin_rintf(x * 1.44269504088896341f);
    float r = __builtin_fmaf(q, -0.693359375f, x);
    r = __builtin_fmaf(q, 2.12194440e-4f, r);
    float p = __builtin_fmaf(1.9875691500e-4f, r, 1.3981999507e-3f);
    p = __builtin_fmaf(p, r, 8.3334519073e-3f);
    p = __builtin_fmaf(p, r, 4.1665795894e-2f);
    p = __builtin_fmaf(p, r, 1.6666665459e-1f);
    p = __builtin_fmaf(p, r, 5.0000001201e-1f);
    const float r2 = r * r;
    p = __builtin_fmaf(p, r2, r);
    p = p + 1.0f;
    return __builtin_ldexpf(p, (int)q);
}

__global__ void prep_T(const float* __restrict__ w1, const float* __restrict__ w2,
                       float* __restrict__ w1t, float* __restrict__ w2t) {
    const int c = blockIdx.x;    // 256
    const int m = threadIdx.x;   // 128
    w1t[c * MEDC + m] = w1[m * CIN + c];
    // w2t permuted so channels {q, q+64, q+128, q+192} form one float4:
    // w2t[m][4q + ci] = w2[q + 64*ci][m]
    const int q  = c & 63;
    const int ci = c >> 6;
    w2t[m * CIN + q * 4 + ci] = w2[c * MEDC + m];
}

// ---------- flip-merge bitonic sort: 256 keys as positive f64 denormals ----------
// position e = 16*u + r  (u = lane-in-16, r = reg) ; fully ascending network.
// Keys: ((u64)sig_bits << 8) | (255 - c)  < 2^40  -> positive f64 denormal,
// IEEE-ordered identically to u64 compare; f64 denorms never flushed; all keys
// distinct (channel payload) so min/max ties are impossible.

template<int MASK>
__device__ __forceinline__ void intraX(double (&k)[16]) {
#pragma unroll
    for (int r = 0; r < 16; ++r) {
        if (r < (r ^ MASK)) {
            const double a = k[r], bb = k[r ^ MASK];
            k[r]        = fmin(a, bb);
            k[r ^ MASK] = fmax(a, bb);
        }
    }
}

template<int SWZ>
__device__ __forceinline__ double swzd(double v) {
    const u64 x = (u64)__double_as_longlong(v);
    const int lo = __builtin_amdgcn_ds_swizzle((int)(u32)x, SWZ);
    const int hi = __builtin_amdgcn_ds_swizzle((int)(u32)(x >> 32), SWZ);
    return __longlong_as_double((long long)(((u64)(u32)hi << 32) | (u64)(u32)lo));
}

// flip substep of merge L: pair e <-> e^(L-1): lane u <-> u^M (SWZ), reg r <-> r^15
template<int SWZ, int UB>
__device__ __forceinline__ void crossFlip(double (&k)[16], const int u) {
    const bool keepmin = (u & UB) == 0;
#pragma unroll
    for (int r = 0; r < 8; ++r) {
        const int q = r ^ 15;
        const double o1 = swzd<SWZ>(k[q]);   // partner's old k[q]
        const double o2 = swzd<SWZ>(k[r]);   // partner's old k[r]
        const double mn1 = fmin(k[r], o1), mx1 = fmax(k[r], o1);
        const double mn2 = fmin(k[q], o2), mx2 = fmax(k[q], o2);
        k[r] = keepmin ? mn1 : mx1;
        k[q] = keepmin ? mn2 : mx2;
    }
}

// uniform cross substep: pair lane u <-> u^M, same reg
template<int SWZ, int UB>
__device__ __forceinline__ void crossU(double (&k)[16], const int u) {
    const bool keepmin = (u & UB) == 0;
#pragma unroll
    for (int r = 0; r < 16; ++r) {
        const double o = swzd<SWZ>(k[r]);
        const double mn = fmin(k[r], o), mx = fmax(k[r], o);
        k[r] = keepmin ? mn : mx;
    }
}

// (256,3): empirically the allocator budget is ~256/min_waves VGPR -> 85 cap,
// kernel compiles to ~64 with no spill; residency then VGPR-bound (~16 waves/CU).
__global__ __launch_bounds__(256, 3)
void csel_main(const float* __restrict__ x,
               const float* __restrict__ w1t, const float* __restrict__ w2t,
               const float* __restrict__ b1, const float* __restrict__ b2,
               float* __restrict__ out) {
    // xs: x tile (stride 20), later overwritten in-place with prod = x * x_
    __shared__ __align__(16) float xs[CIN * 20];   // 20480 B
    // hs: h round-trip buffer for GEMM2 wave-uniform broadcast reads
    __shared__ __align__(16) float hs[MEDC * 20];  // 10240 B (total 30720)

    const int t    = threadIdx.x;
    const int pix0 = blockIdx.x * TP;
    const int b    = pix0 / HWSZ;
    const int hw0  = pix0 % HWSZ;
    const float* xb = x + (size_t)b * CIN * HWSZ + hw0;

    // ---- stage x tile: 256 channels x 16 pixels ----
    {
        const int p  = t & (TP - 1);
        const int c0 = t >> 4;
        #pragma unroll
        for (int i = 0; i < 16; ++i) {
            const int c = c0 + i * 16;
            xs[c * 20 + p] = xb[(size_t)c * HWSZ + p];
        }
    }
    __syncthreads();

    // ---- GEMM1: h[m][p] = sequential fp32 FMA chain over c ascending ----
    // Lane lw of wave wq computes m = {2lw, 2lw+1} for pixels {4wq..4wq+3}.
    const int lw = t & 63;
    const int wq = t >> 6;
    const int ml = lw * 2;
    const float b1a = b1[ml];
    const float b1b = b1[ml + 1];
    float a1[2][4] = {{0.f,0.f,0.f,0.f},{0.f,0.f,0.f,0.f}};

    #pragma unroll 4
    for (int c = 0; c < CIN; ++c) {
        const float2 wv = *(const float2*)&w1t[c * MEDC + ml];
        const float4 xv = *(const float4*)&xs[c * 20 + wq * 4];   // wave-uniform broadcast
        a1[0][0] = fmaf(wv.x, xv.x, a1[0][0]);
        a1[0][1] = fmaf(wv.x, xv.y, a1[0][1]);
        a1[0][2] = fmaf(wv.x, xv.z, a1[0][2]);
        a1[0][3] = fmaf(wv.x, xv.w, a1[0][3]);
        a1[1][0] = fmaf(wv.y, xv.x, a1[1][0]);
        a1[1][1] = fmaf(wv.y, xv.y, a1[1][1]);
        a1[1][2] = fmaf(wv.y, xv.z, a1[1][2]);
        a1[1][3] = fmaf(wv.y, xv.w, a1[1][3]);
    }
    // write h to LDS: two b128 stores per lane (rows ml, ml+1, pixels 4wq..4wq+3)
    {
        float4 h0, h1;
        h0.x = a1[0][0] + b1a; h0.y = a1[0][1] + b1a;
        h0.z = a1[0][2] + b1a; h0.w = a1[0][3] + b1a;
        h1.x = a1[1][0] + b1b; h1.y = a1[1][1] + b1b;
        h1.z = a1[1][2] + b1b; h1.w = a1[1][3] + b1b;
        *(float4*)&hs[ml * 20 + wq * 4]       = h0;
        *(float4*)&hs[(ml + 1) * 20 + wq * 4] = h1;
    }
    __syncthreads();   // hs ready; also: all GEMM1 xs reads complete (prod may overwrite)

    // ---- GEMM2: lane lw owns channels {lw+64ci} x pixels {4wq+pj}.
    // Per m: ONE w2t float4 (coalesced, prefetch ring) + ONE hs float4 broadcast.
    const float b2v0 = b2[lw];
    const float b2v1 = b2[lw + 64];
    const float b2v2 = b2[lw + 128];
    const float b2v3 = b2[lw + 192];
    const float* w2p = w2t + lw * 4;

    float4 wbuf[4];
    #pragma unroll
    for (int m0 = 0; m0 < 4; ++m0)
        wbuf[m0] = *(const float4*)&w2p[m0 * CIN];

    float a2[4][4];
    #pragma unroll
    for (int i = 0; i < 4; ++i)
        #pragma unroll
        for (int j = 0; j < 4; ++j) a2[i][j] = 0.f;

    #pragma unroll
    for (int m = 0; m < MEDC; ++m) {
        const float4 wv = wbuf[m & 3];
        const float4 hv = *(const float4*)&hs[m * 20 + wq * 4];   // wave-uniform broadcast
        a2[0][0] = fmaf(wv.x, hv.x, a2[0][0]);
        a2[0][1] = fmaf(wv.x, hv.y, a2[0][1]);
        a2[0][2] = fmaf(wv.x, hv.z, a2[0][2]);
        a2[0][3] = fmaf(wv.x, hv.w, a2[0][3]);
        a2[1][0] = fmaf(wv.y, hv.x, a2[1][0]);
        a2[1][1] = fmaf(wv.y, hv.y, a2[1][1]);
        a2[1][2] = fmaf(wv.y, hv.z, a2[1][2]);
        a2[1][3] = fmaf(wv.y, hv.w, a2[1][3]);
        a2[2][0] = fmaf(wv.z, hv.x, a2[2][0]);
        a2[2][1] = fmaf(wv.z, hv.y, a2[2][1]);
        a2[2][2] = fmaf(wv.z, hv.z, a2[2][2]);
        a2[2][3] = fmaf(wv.z, hv.w, a2[2][3]);
        a2[3][0] = fmaf(wv.w, hv.x, a2[3][0]);
        a2[3][1] = fmaf(wv.w, hv.y, a2[3][1]);
        a2[3][2] = fmaf(wv.w, hv.z, a2[3][2]);
        a2[3][3] = fmaf(wv.w, hv.w, a2[3][3]);
        if (m + 4 < MEDC)
            wbuf[m & 3] = *(const float4*)&w2p[(m + 4) * CIN];
    }
    float xv32[4][4];
    #pragma unroll
    for (int pj = 0; pj < 4; ++pj) {
        xv32[0][pj] = a2[0][pj] + b2v0;
        xv32[1][pj] = a2[1][pj] + b2v1;
        xv32[2][pj] = a2[2][pj] + b2v2;
        xv32[3][pj] = a2[3][pj] + b2v3;
    }
    // no barrier needed: prod writes xs (GEMM1 reads barrier'd above); hs never reused

    // ---- sigmoid bits -> registers; prod = x * x_ in-place over xs ----
    u32 sv[4][4];
    #pragma unroll
    for (int ci = 0; ci < 4; ++ci) {
        const int c = lw + 64 * ci;
        #pragma unroll
        for (int pj = 0; pj < 4; ++pj) {
#pragma clang fp contract(off)
            const int p2 = wq * 4 + pj;
            const float e  = numpy_expf(-xv32[ci][pj]);
            const float dd = 1.0f + e;
            const float s  = 1.0f / dd;
            sv[ci][pj] = __float_as_uint(s);
            xs[c * 20 + p2] = xs[c * 20 + p2] * xv32[ci][pj];
        }
    }
    __syncthreads();   // prod writes complete before epilogue gathers (sort is reg-only)

    // ---- 4x4 register transpose over (lane-quarter a, pixel-reg b) ----
    // After: lane (a,u), reg b, ci holds sig bits of channel c = u + 16b + 64ci,
    // pixel 4wq + a  (= this lane's own sort pixel t>>4).
    const int a0 = (t >> 4) & 1;
    const int a1b = (t >> 5) & 1;
    #pragma unroll
    for (int ci = 0; ci < 4; ++ci) {
        {   // round 1: partner lane^16, pairs (b, b^1)
            const u32 s0 = (u32)__builtin_amdgcn_ds_swizzle((int)sv[ci][1], 0x401F);
            const u32 s1 = (u32)__builtin_amdgcn_ds_swizzle((int)sv[ci][0], 0x401F);
            const u32 s2 = (u32)__builtin_amdgcn_ds_swizzle((int)sv[ci][3], 0x401F);
            const u32 s3 = (u32)__builtin_amdgcn_ds_swizzle((int)sv[ci][2], 0x401F);
            sv[ci][0] = a0 ? s0 : sv[ci][0];
            sv[ci][1] = a0 ? sv[ci][1] : s1;
            sv[ci][2] = a0 ? s2 : sv[ci][2];
            sv[ci][3] = a0 ? sv[ci][3] : s3;
        }
        {   // round 2: partner lane^32, pairs (b, b^2)
            const u32 s0 = (u32)__shfl_xor((int)sv[ci][2], 32, 64);
            const u32 s1 = (u32)__shfl_xor((int)sv[ci][3], 32, 64);
            const u32 s2 = (u32)__shfl_xor((int)sv[ci][0], 32, 64);
            const u32 s3 = (u32)__shfl_xor((int)sv[ci][1], 32, 64);
            sv[ci][0] = a1b ? s0 : sv[ci][0];
            sv[ci][1] = a1b ? s1 : sv[ci][1];
            sv[ci][2] = a1b ? sv[ci][2] : s2;
            sv[ci][3] = a1b ? sv[ci][3] : s3;
        }
    }

    // ---- build keys: k[r] holds channel c = u + 16r of this lane's pixel ----
    const int u = t & 15;
    double k[16];
    #pragma unroll
    for (int ci = 0; ci < 4; ++ci) {
        #pragma unroll
        for (int bb = 0; bb < 4; ++bb) {
            const int r = bb + 4 * ci;
            const u64 key = ((u64)sv[ci][bb] << 8) | (u64)(255 - (u + 16 * r));
            k[r] = __longlong_as_double((long long)key);
        }
    }

    // ---- flip-merge bitonic sort, all-ascending min/max network ----
    intraX<1>(k);                                                      // L=2
    intraX<3>(k); intraX<1>(k);                                        // L=4
    intraX<7>(k); intraX<2>(k); intraX<1>(k);                          // L=8
    intraX<15>(k); intraX<4>(k); intraX<2>(k); intraX<1>(k);           // L=16
    crossFlip<0x041F,1>(k,u);                                          // L=32
    intraX<8>(k); intraX<4>(k); intraX<2>(k); intraX<1>(k);
    crossFlip<0x0C1F,2>(k,u); crossU<0x041F,1>(k,u);                   // L=64
    intraX<8>(k); intraX<4>(k); intraX<2>(k); intraX<1>(k);
    crossFlip<0x1C1F,4>(k,u); crossU<0x081F,2>(k,u); crossU<0x041F,1>(k,u);   // L=128
    intraX<8>(k); intraX<4>(k); intraX<2>(k); intraX<1>(k);
    crossFlip<0x3C1F,8>(k,u); crossU<0x101F,4>(k,u); crossU<0x081F,2>(k,u); crossU<0x041F,1>(k,u); // L=256
    intraX<8>(k); intraX<4>(k); intraX<2>(k); intraX<1>(k);

    // ---- epilogue: positions e=16u+r, e>=128 hold ranks 127..0 ----
    const int p = t >> 4;
    if (u >= 8) {
        const int rbase = 255 - u * 16;    // rank = rbase - r
        float* ob = out + (size_t)b * KOUT * HWSZ + hw0 + p;
        #pragma unroll
        for (int r = 0; r < 16; ++r) {
            const u64 kb = (u64)__double_as_longlong(k[r]);
            const int c = 255 - (int)(kb & 0xFF);
            ob[(size_t)(rbase - r) * HWSZ] = xs[c * 20 + p];
        }
    }
}

extern "C" void kernel_launch(void* const* d_in, const int* in_sizes, int n_in,
                              void* d_out, int out_size, void* d_ws, size_t ws_size,
                              hipStream_t stream) {
    const float* x  = (const float*)d_in[0];
    const float* w1 = (const float*)d_in[1];
    const float* b1 = (const float*)d_in[2];
    const float* w2 = (const float*)d_in[3];
    const float* b2 = (const float*)d_in[4];

    float* w1t = (float*)d_ws;              // 128 KB
    float* w2t = w1t + CIN * MEDC;          // 128 KB

    prep_T<<<CIN, MEDC, 0, stream>>>(w1, w2, w1t, w2t);
    csel_main<<<(NB * HWSZ) / TP, 256, 0, stream>>>(x, w1t, w2t, b1, b2, (float*)d_out);
}